// Round 23
// baseline (320.356 us; speedup 1.0000x reference)
//
#include <hip/hip_runtime.h>
#include <math.h>

// ---------------------------------------------------------------------------
// GCN 3-layer forward for MI355X.
// R16/R21 known-good structure (320us): interleaved gemm_cnt + counting-sort
//   CSR + wave-per-node deg + bf16 gather aggs + persistent gemms.
// R17-R20 lesson: do NOT fuse agg+gemm (1-row-per-wave TLP wins).
// R22: (a) norm rewrite folded into agg0 (NORMW): lane gathers dis[s],
//   computes nrm=dis[s]*ew*dis[row], writes pair back + aggregates. Deletes
//   k_norm_csr (one pass of 12.8MB r + 12.8MB w -> just +12.8MB w in agg0).
//   Determinism: k_place refreshes ew-payload each launch before agg0.
//   (b) XB 256->128 (32K threads still saturate TCC atomics; +1 gemm slot).
// ---------------------------------------------------------------------------

__device__ __forceinline__ unsigned short f2bf(float f) {   // RNE fp32->bf16
    unsigned u = __float_as_uint(f);
    u += 0x7FFFu + ((u >> 16) & 1u);
    return (unsigned short)(u >> 16);
}
__device__ __forceinline__ float bf2f(unsigned short h) {
    return __uint_as_float(((unsigned)h) << 16);
}

// ---- scan: per-block exclusive (scan1) + fused block-offset apply (scan3m) --
__global__ void k_scan1(const int* __restrict__ cnt, int* __restrict__ excl,
                        int* __restrict__ bsum, int n) {
    __shared__ int sm[256];
    int tid = threadIdx.x;
    int i = blockIdx.x * 256 + tid;
    int v = (i < n) ? cnt[i] : 0;
    sm[tid] = v;
    __syncthreads();
    for (int off = 1; off < 256; off <<= 1) {
        int t = (tid >= off) ? sm[tid - off] : 0;
        __syncthreads();
        sm[tid] += t;
        __syncthreads();
    }
    if (i < n) excl[i] = sm[tid] - v;
    if (tid == 255) bsum[blockIdx.x] = sm[255];
}

// Each block computes its own prefix over bsum[0..blk) (replaces scan2+scan3).
__global__ void k_scan3m(int* __restrict__ rowptr, const int* __restrict__ bsum,
                         int n, int E) {
    __shared__ int red[256];
    const int blk = (int)blockIdx.x, tid = (int)threadIdx.x;
    int s = 0;
    for (int j = tid; j < blk; j += 256) s += bsum[j];
    red[tid] = s;
    __syncthreads();
    for (int off = 128; off; off >>= 1) {
        if (tid < off) red[tid] += red[tid + off];
        __syncthreads();
    }
    const int prefix = red[0];
    int i = blk * 256 + tid;
    if (i < n) rowptr[i] += prefix;
    if (i == 0) rowptr[n] = E;
}

// Place edges into dst-grouped slots (NO atomic): 8B packed {src, ew}.
__global__ void k_place(const int* __restrict__ src, const int* __restrict__ dst,
                        const float* __restrict__ ew, const int* __restrict__ rowptr,
                        const int* __restrict__ pos, unsigned long long* __restrict__ pairP,
                        int E) {
    int e = blockIdx.x * blockDim.x + threadIdx.x;
    if (e < E) {
        int d = dst[e];
        int p = rowptr[d] + pos[e];
        unsigned long long pk = (unsigned long long)__float_as_uint(ew[e]) << 32
                              | (unsigned int)src[e];
        pairP[p] = pk;
    }
}

// Wave-per-node: dis = rsqrt(1 + sum ew). Coalesced 64-slot reads + shuffle.
__global__ __launch_bounds__(256) void k_deg_dis(
    const unsigned long long* __restrict__ pairP,
    const int* __restrict__ rowptr, float* __restrict__ dis, int n)
{
    const int lane = threadIdx.x & 63;
    int row = (int)((blockIdx.x * blockDim.x + threadIdx.x) >> 6);
    if (row >= n) return;
    row = __builtin_amdgcn_readfirstlane(row);
    const int a = rowptr[row], b = rowptr[row + 1];
    float s = 0.f;
    for (int idx = a + lane; idx < b; idx += 64)
        s += __uint_as_float((unsigned int)(pairP[idx] >> 32));
#pragma unroll
    for (int off = 32; off; off >>= 1) s += __shfl_xor(s, off);
    if (lane == 0) {
        float d = 1.0f + s;   // self-loop
        dis[row] = (d > 0.f) ? rsqrtf(d) : 0.f;
    }
}

// Tiled GEMM body: HB(bf16) = act(X fp32)@W, BM64xBN64xBK32, 4x4 reg tile,
// reg-prefetch of tile t+1, T-loop NOT unrolled (R9 lesson).
template<int K, int NOUT, bool RELU_IN>
__device__ __forceinline__ void gemm_tile_body(
    const float* __restrict__ X, const float* __restrict__ W,
    unsigned short* __restrict__ HB, int nrows, int tile)
{
    constexpr int BM = 64, BN = 64, BK = 32;
    constexpr int T  = K / BK;
    __shared__ float As[BK][BM + 4];   // As[k][m]
    __shared__ float Bs[BK][BN + 4];

    const int tid = (int)threadIdx.x;
    const int tx  = tid & 15;
    const int ty  = tid >> 4;
    const int r0  = tile * BM;

    const int ar = tid >> 3;
    const int aq = tid & 7;
    const int bk = tid >> 4;
    const int bc = tid & 15;

    const int rowA0 = min(r0 + ar,      nrows - 1);
    const int rowA1 = min(r0 + ar + 32, nrows - 1);
    const float* pA0 = X + (size_t)rowA0 * K + aq * 4;
    const float* pA1 = X + (size_t)rowA1 * K + aq * 4;
    const bool wok = (bc * 4 + 3 < NOUT);
    const float* pB0 = W + (size_t)bk * NOUT + bc * 4;
    const float* pB1 = W + (size_t)(bk + 16) * NOUT + bc * 4;
    const float4 z4 = make_float4(0.f, 0.f, 0.f, 0.f);

    float4 ra0, ra1, rb0, rb1;
    ra0 = *(const float4*)pA0;
    ra1 = *(const float4*)pA1;
    rb0 = wok ? *(const float4*)pB0 : z4;
    rb1 = wok ? *(const float4*)pB1 : z4;

    float acc[4][4] = {};

#pragma unroll 1
    for (int t = 0; t < T; ++t) {
        if (RELU_IN) {
            ra0.x = fmaxf(ra0.x, 0.f); ra0.y = fmaxf(ra0.y, 0.f);
            ra0.z = fmaxf(ra0.z, 0.f); ra0.w = fmaxf(ra0.w, 0.f);
            ra1.x = fmaxf(ra1.x, 0.f); ra1.y = fmaxf(ra1.y, 0.f);
            ra1.z = fmaxf(ra1.z, 0.f); ra1.w = fmaxf(ra1.w, 0.f);
        }
        As[aq * 4 + 0][ar]      = ra0.x;
        As[aq * 4 + 1][ar]      = ra0.y;
        As[aq * 4 + 2][ar]      = ra0.z;
        As[aq * 4 + 3][ar]      = ra0.w;
        As[aq * 4 + 0][ar + 32] = ra1.x;
        As[aq * 4 + 1][ar + 32] = ra1.y;
        As[aq * 4 + 2][ar + 32] = ra1.z;
        As[aq * 4 + 3][ar + 32] = ra1.w;
        *(float4*)&Bs[bk][bc * 4]      = rb0;
        *(float4*)&Bs[bk + 16][bc * 4] = rb1;
        __syncthreads();

        if (t + 1 < T) {
            const int ko = (t + 1) * BK;
            ra0 = *(const float4*)(pA0 + ko);
            ra1 = *(const float4*)(pA1 + ko);
            rb0 = wok ? *(const float4*)(pB0 + (size_t)ko * NOUT) : z4;
            rb1 = wok ? *(const float4*)(pB1 + (size_t)ko * NOUT) : z4;
        }

#pragma unroll
        for (int kk = 0; kk < BK; ++kk) {
            float4 a = *(const float4*)&As[kk][ty * 4];
            float4 b = *(const float4*)&Bs[kk][tx * 4];
            acc[0][0] += a.x * b.x; acc[0][1] += a.x * b.y; acc[0][2] += a.x * b.z; acc[0][3] += a.x * b.w;
            acc[1][0] += a.y * b.x; acc[1][1] += a.y * b.y; acc[1][2] += a.y * b.z; acc[1][3] += a.y * b.w;
            acc[2][0] += a.z * b.x; acc[2][1] += a.z * b.y; acc[2][2] += a.z * b.z; acc[2][3] += a.z * b.w;
            acc[3][0] += a.w * b.x; acc[3][1] += a.w * b.y; acc[3][2] += a.w * b.z; acc[3][3] += a.w * b.w;
        }
        __syncthreads();
    }

    if (tx * 4 + 3 < NOUT) {
#pragma unroll
        for (int i = 0; i < 4; ++i) {
            int row = r0 + ty * 4 + i;
            if (row < nrows) {
                ushort4 hv;
                hv.x = f2bf(acc[i][0]); hv.y = f2bf(acc[i][1]);
                hv.z = f2bf(acc[i][2]); hv.w = f2bf(acc[i][3]);
                *(ushort4*)&HB[(size_t)row * NOUT + tx * 4] = hv;
            }
        }
    }
}

// Persistent GEMM (layers 1 & 2): grid-stride over row tiles; W stays L2-hot.
template<int K, int NOUT, bool RELU_IN>
__global__ __launch_bounds__(256) void k_gemm(
    const float* __restrict__ X, const float* __restrict__ W,
    unsigned short* __restrict__ HB, int nrows, int ntiles)
{
#pragma unroll 1
    for (int tile = (int)blockIdx.x; tile < ntiles; tile += (int)gridDim.x)
        gemm_tile_body<K, NOUT, RELU_IN>(X, W, HB, nrows, tile);
}

// Fused, INTERLEAVED: paired region [0, 2*min(ntiles,ncnt)): even=cnt,
// odd=gemm; tail = leftover blocks of the larger role.
template<int K, int NOUT, bool RELU_IN>
__global__ __launch_bounds__(256) void k_gemm_cnt(
    const float* __restrict__ X, const float* __restrict__ W,
    unsigned short* __restrict__ HB, int nrows, int ntiles, int ncnt,
    const int* __restrict__ dst, int* __restrict__ cnt, int* __restrict__ pos, int E)
{
    const int b  = (int)blockIdx.x;
    const int m  = min(ntiles, ncnt);
    bool isCnt; int idx;
    if (b < 2 * m) {
        isCnt = ((b & 1) == 0);
        idx   = b >> 1;
    } else {
        int rem = b - 2 * m;
        isCnt = (ncnt > ntiles);
        idx   = m + rem;
    }
    if (!isCnt) {
        gemm_tile_body<K, NOUT, RELU_IN>(X, W, HB, nrows, idx);
    } else {
        int e0     = idx * 256 + (int)threadIdx.x;
        int stride = ncnt * 256;
        for (int e = e0; e < E; e += stride)
            pos[e] = atomicAdd(&cnt[dst[e]], 1);
    }
}

// Gather aggregation: one wave per node, lane = feature. No atomics.
// Pairs staged via ONE coalesced 512B wave-load per 64 slots; unroll-4.
// NORMW (agg0 only): payload arrives as ew; lane computes nrm =
// dis[s]*ew*dis[row], writes the pair back (coalesced) and aggregates with
// nrm. Layers 1/2 then read nrm directly. k_place refreshes ew each launch.
template<int F, bool LSM, bool NORMW>
__global__ __launch_bounds__(256) void k_node_agg(
    const unsigned short* __restrict__ hB, const float* __restrict__ dis,
    const float* __restrict__ bias, const int* __restrict__ rowptr,
    unsigned long long* __restrict__ pairP,
    float* __restrict__ out, int n)
{
    __shared__ unsigned long long pl[4][64];   // 2KB: 64 pairs per wave
    const int lane = threadIdx.x & 63;
    const int wid  = (threadIdx.x >> 6) & 3;
    int row = (int)((blockIdx.x * blockDim.x + threadIdx.x) >> 6);
    if (row >= n) return;
    row = __builtin_amdgcn_readfirstlane(row);   // wave-uniform -> SGPR addrs

    const int a = rowptr[row], b = rowptr[row + 1];
    float d  = dis[row];
    float dd = d * d;
    float sum = 0.f;
    if (lane < F) sum = bf2f(hB[(size_t)row * F + lane]) * dd + bias[lane];

    for (int base = a; base < b; base += 64) {
        int idx = base + lane;
        unsigned long long pk = (idx < b) ? pairP[idx] : 0ull;  // coalesced 512B
        if (NORMW) {
            if (idx < b) {
                int   sl = (int)(unsigned int)pk;
                float wl = __uint_as_float((unsigned int)(pk >> 32));
                float nr = dis[sl] * wl * d;          // dis[s]*ew*dis[row]
                pk = ((unsigned long long)__float_as_uint(nr) << 32)
                   | (unsigned int)sl;
                pairP[idx] = pk;                      // coalesced write-back
            }
        }
        pl[wid][lane] = pk;
        int c = min(64, b - base);
        int j = 0;
        for (; j + 4 <= c; j += 4) {
            unsigned long long p0 = pl[wid][j],     p1 = pl[wid][j + 1];
            unsigned long long p2 = pl[wid][j + 2], p3 = pl[wid][j + 3];
            int   s0 = (int)(unsigned int)p0, s1 = (int)(unsigned int)p1;
            int   s2 = (int)(unsigned int)p2, s3 = (int)(unsigned int)p3;
            float w0 = __uint_as_float((unsigned int)(p0 >> 32));
            float w1 = __uint_as_float((unsigned int)(p1 >> 32));
            float w2 = __uint_as_float((unsigned int)(p2 >> 32));
            float w3 = __uint_as_float((unsigned int)(p3 >> 32));
            if (lane < F) {
                sum += bf2f(hB[(size_t)s0 * F + lane]) * w0;
                sum += bf2f(hB[(size_t)s1 * F + lane]) * w1;
                sum += bf2f(hB[(size_t)s2 * F + lane]) * w2;
                sum += bf2f(hB[(size_t)s3 * F + lane]) * w3;
            }
        }
        for (; j < c; ++j) {
            unsigned long long p = pl[wid][j];
            int s = (int)(unsigned int)p;
            float w = __uint_as_float((unsigned int)(p >> 32));
            if (lane < F) sum += bf2f(hB[(size_t)s * F + lane]) * w;
        }
    }

    if (LSM) {
        float v = (lane < F) ? sum : -INFINITY;
        float m = v;
#pragma unroll
        for (int off = 32; off; off >>= 1) m = fmaxf(m, __shfl_xor(m, off));
        float e = (lane < F) ? expf(v - m) : 0.f;
        float s2 = e;
#pragma unroll
        for (int off = 32; off; off >>= 1) s2 += __shfl_xor(s2, off);
        float ls = logf(s2);
        if (lane < F) out[(size_t)row * F + lane] = v - m - ls;
    } else {
        if (lane < F) out[(size_t)row * F + lane] = sum;
    }
}

extern "C" void kernel_launch(void* const* d_in, const int* in_sizes, int n_in,
                              void* d_out, int out_size, void* d_ws, size_t ws_size,
                              hipStream_t stream) {
    const float* x  = (const float*)d_in[0];
    const int*   ei = (const int*)  d_in[1];
    const float* ew = (const float*)d_in[2];
    const float* W0 = (const float*)d_in[3];
    const float* b0 = (const float*)d_in[4];
    const float* W1 = (const float*)d_in[5];
    const float* b1 = (const float*)d_in[6];
    const float* W2 = (const float*)d_in[7];
    const float* b2 = (const float*)d_in[8];

    const int E   = in_sizes[2];            // 1600000
    const int H   = in_sizes[4];            // 64
    const int Fin = in_sizes[3] / H;        // 256
    const int N   = in_sizes[0] / Fin;      // 100000
    (void)n_in; (void)out_size; (void)ws_size;

    const int* srcv = ei;                   // edge_index[0]
    const int* dstv = ei + E;               // edge_index[1]

    // ---- workspace layout ----
    float* ws = (float*)d_ws;
    size_t o = 0;
    auto alloc = [&](size_t cnt_) { size_t p = o; o += (cnt_ + 63) & ~(size_t)63; return p; };
    float* dis   = ws + alloc(N);
    float* bufB  = ws + alloc((size_t)N * 64);               // agg out (fp32 trunk)
    unsigned short* hB = (unsigned short*)(ws + alloc((size_t)N * 32));  // bf16 h
    unsigned long long* pairP = (unsigned long long*)(ws + alloc((size_t)E * 2));
    int*   rowptr= (int*)(ws + alloc(N + 1));
    int*   cnt   = (int*)(ws + alloc(N));
    int*   pos   = (int*)(ws + alloc(E));
    int*   bsum  = (int*)(ws + alloc(512));
    float* outf  = (float*)d_out;                            // N*40

    const int TB  = 256;
    const int nb1 = (N + 255) / 256;                 // scan blocks (391)
    const int ntiles = (N + 63) / 64;                // 1563 gemm tiles
    const int XB  = 128;                             // cnt blocks (R22: 256->128)

    // ---- fused interleaved: gemm L0 || counting histogram ----
    (void)hipMemsetAsync(cnt, 0, (size_t)N * sizeof(int), stream);
    {
        const int m = (ntiles < XB) ? ntiles : XB;
        const int grid = 2 * m + ((ntiles > XB) ? (ntiles - XB) : (XB - ntiles));
        k_gemm_cnt<256, 64, false><<<grid, TB, 0, stream>>>(
            x, W0, hB, N, ntiles, XB, dstv, cnt, pos, E);
    }

    // ---- scan cnt -> rowptr (2 kernels) ----
    k_scan1 <<<nb1, 256, 0, stream>>>(cnt, rowptr, bsum, N);
    k_scan3m<<<nb1, 256, 0, stream>>>(rowptr, bsum, N, E);

    // ---- place packed pairs (no atomic; payload = ew) ----
    k_place<<<(E + TB - 1) / TB, TB, 0, stream>>>(srcv, dstv, ew, rowptr, pos, pairP, E);

    const int aggGrid = (N * 64 + TB - 1) / TB;      // one wave per node

    // ---- dis over CSR (wave-per-node, coalesced) ----
    k_deg_dis<<<aggGrid, TB, 0, stream>>>(pairP, rowptr, dis, N);

    // ---- layer 0 aggregate + fused norm rewrite (ew -> nrm in pairP) ----
    k_node_agg<64, false, true><<<aggGrid, TB, 0, stream>>>(hB, dis, b0, rowptr, pairP, bufB, N);

    // ---- layer 1: 64 -> 64 (relu on load), persistent grid ----
    k_gemm<64, 64, true><<<512, TB, 0, stream>>>(bufB, W1, hB, N, ntiles);
    k_node_agg<64, false, false><<<aggGrid, TB, 0, stream>>>(hB, dis, b1, rowptr, pairP, bufB, N);

    // ---- layer 2: 64 -> 40, aggregate + fused log_softmax into d_out ----
    k_gemm<64, 40, true><<<512, TB, 0, stream>>>(bufB, W2, hB, N, ntiles);
    k_node_agg<40, true, false><<<aggGrid, TB, 0, stream>>>(hB, dis, b2, rowptr, pairP, outf, N);
}

// Round 24
// 313.862 us; speedup vs baseline: 1.0207x; 1.0207x over previous
//
#include <hip/hip_runtime.h>
#include <math.h>

// ---------------------------------------------------------------------------
// GCN 3-layer forward for MI355X.
// R21 known-good (320us). R23 A/B result: NORMW fold GOOD (norm kernel
//   deleted, ~10us saved); XB 128 BAD (fused kernel 84->95us; cnt-phase
//   needs >=64K threads: measured XB gradient 1024->88.5, 256->82.5,
//   128->95). R24: keep NORMW, revert XB to 256.
// ---------------------------------------------------------------------------

__device__ __forceinline__ unsigned short f2bf(float f) {   // RNE fp32->bf16
    unsigned u = __float_as_uint(f);
    u += 0x7FFFu + ((u >> 16) & 1u);
    return (unsigned short)(u >> 16);
}
__device__ __forceinline__ float bf2f(unsigned short h) {
    return __uint_as_float(((unsigned)h) << 16);
}

// ---- scan: per-block exclusive (scan1) + fused block-offset apply (scan3m) --
__global__ void k_scan1(const int* __restrict__ cnt, int* __restrict__ excl,
                        int* __restrict__ bsum, int n) {
    __shared__ int sm[256];
    int tid = threadIdx.x;
    int i = blockIdx.x * 256 + tid;
    int v = (i < n) ? cnt[i] : 0;
    sm[tid] = v;
    __syncthreads();
    for (int off = 1; off < 256; off <<= 1) {
        int t = (tid >= off) ? sm[tid - off] : 0;
        __syncthreads();
        sm[tid] += t;
        __syncthreads();
    }
    if (i < n) excl[i] = sm[tid] - v;
    if (tid == 255) bsum[blockIdx.x] = sm[255];
}

// Each block computes its own prefix over bsum[0..blk) (replaces scan2+scan3).
__global__ void k_scan3m(int* __restrict__ rowptr, const int* __restrict__ bsum,
                         int n, int E) {
    __shared__ int red[256];
    const int blk = (int)blockIdx.x, tid = (int)threadIdx.x;
    int s = 0;
    for (int j = tid; j < blk; j += 256) s += bsum[j];
    red[tid] = s;
    __syncthreads();
    for (int off = 128; off; off >>= 1) {
        if (tid < off) red[tid] += red[tid + off];
        __syncthreads();
    }
    const int prefix = red[0];
    int i = blk * 256 + tid;
    if (i < n) rowptr[i] += prefix;
    if (i == 0) rowptr[n] = E;
}

// Place edges into dst-grouped slots (NO atomic): 8B packed {src, ew}.
__global__ void k_place(const int* __restrict__ src, const int* __restrict__ dst,
                        const float* __restrict__ ew, const int* __restrict__ rowptr,
                        const int* __restrict__ pos, unsigned long long* __restrict__ pairP,
                        int E) {
    int e = blockIdx.x * blockDim.x + threadIdx.x;
    if (e < E) {
        int d = dst[e];
        int p = rowptr[d] + pos[e];
        unsigned long long pk = (unsigned long long)__float_as_uint(ew[e]) << 32
                              | (unsigned int)src[e];
        pairP[p] = pk;
    }
}

// Wave-per-node: dis = rsqrt(1 + sum ew). Coalesced 64-slot reads + shuffle.
__global__ __launch_bounds__(256) void k_deg_dis(
    const unsigned long long* __restrict__ pairP,
    const int* __restrict__ rowptr, float* __restrict__ dis, int n)
{
    const int lane = threadIdx.x & 63;
    int row = (int)((blockIdx.x * blockDim.x + threadIdx.x) >> 6);
    if (row >= n) return;
    row = __builtin_amdgcn_readfirstlane(row);
    const int a = rowptr[row], b = rowptr[row + 1];
    float s = 0.f;
    for (int idx = a + lane; idx < b; idx += 64)
        s += __uint_as_float((unsigned int)(pairP[idx] >> 32));
#pragma unroll
    for (int off = 32; off; off >>= 1) s += __shfl_xor(s, off);
    if (lane == 0) {
        float d = 1.0f + s;   // self-loop
        dis[row] = (d > 0.f) ? rsqrtf(d) : 0.f;
    }
}

// Tiled GEMM body: HB(bf16) = act(X fp32)@W, BM64xBN64xBK32, 4x4 reg tile,
// reg-prefetch of tile t+1, T-loop NOT unrolled (R9 lesson).
template<int K, int NOUT, bool RELU_IN>
__device__ __forceinline__ void gemm_tile_body(
    const float* __restrict__ X, const float* __restrict__ W,
    unsigned short* __restrict__ HB, int nrows, int tile)
{
    constexpr int BM = 64, BN = 64, BK = 32;
    constexpr int T  = K / BK;
    __shared__ float As[BK][BM + 4];   // As[k][m]
    __shared__ float Bs[BK][BN + 4];

    const int tid = (int)threadIdx.x;
    const int tx  = tid & 15;
    const int ty  = tid >> 4;
    const int r0  = tile * BM;

    const int ar = tid >> 3;
    const int aq = tid & 7;
    const int bk = tid >> 4;
    const int bc = tid & 15;

    const int rowA0 = min(r0 + ar,      nrows - 1);
    const int rowA1 = min(r0 + ar + 32, nrows - 1);
    const float* pA0 = X + (size_t)rowA0 * K + aq * 4;
    const float* pA1 = X + (size_t)rowA1 * K + aq * 4;
    const bool wok = (bc * 4 + 3 < NOUT);
    const float* pB0 = W + (size_t)bk * NOUT + bc * 4;
    const float* pB1 = W + (size_t)(bk + 16) * NOUT + bc * 4;
    const float4 z4 = make_float4(0.f, 0.f, 0.f, 0.f);

    float4 ra0, ra1, rb0, rb1;
    ra0 = *(const float4*)pA0;
    ra1 = *(const float4*)pA1;
    rb0 = wok ? *(const float4*)pB0 : z4;
    rb1 = wok ? *(const float4*)pB1 : z4;

    float acc[4][4] = {};

#pragma unroll 1
    for (int t = 0; t < T; ++t) {
        if (RELU_IN) {
            ra0.x = fmaxf(ra0.x, 0.f); ra0.y = fmaxf(ra0.y, 0.f);
            ra0.z = fmaxf(ra0.z, 0.f); ra0.w = fmaxf(ra0.w, 0.f);
            ra1.x = fmaxf(ra1.x, 0.f); ra1.y = fmaxf(ra1.y, 0.f);
            ra1.z = fmaxf(ra1.z, 0.f); ra1.w = fmaxf(ra1.w, 0.f);
        }
        As[aq * 4 + 0][ar]      = ra0.x;
        As[aq * 4 + 1][ar]      = ra0.y;
        As[aq * 4 + 2][ar]      = ra0.z;
        As[aq * 4 + 3][ar]      = ra0.w;
        As[aq * 4 + 0][ar + 32] = ra1.x;
        As[aq * 4 + 1][ar + 32] = ra1.y;
        As[aq * 4 + 2][ar + 32] = ra1.z;
        As[aq * 4 + 3][ar + 32] = ra1.w;
        *(float4*)&Bs[bk][bc * 4]      = rb0;
        *(float4*)&Bs[bk + 16][bc * 4] = rb1;
        __syncthreads();

        if (t + 1 < T) {
            const int ko = (t + 1) * BK;
            ra0 = *(const float4*)(pA0 + ko);
            ra1 = *(const float4*)(pA1 + ko);
            rb0 = wok ? *(const float4*)(pB0 + (size_t)ko * NOUT) : z4;
            rb1 = wok ? *(const float4*)(pB1 + (size_t)ko * NOUT) : z4;
        }

#pragma unroll
        for (int kk = 0; kk < BK; ++kk) {
            float4 a = *(const float4*)&As[kk][ty * 4];
            float4 b = *(const float4*)&Bs[kk][tx * 4];
            acc[0][0] += a.x * b.x; acc[0][1] += a.x * b.y; acc[0][2] += a.x * b.z; acc[0][3] += a.x * b.w;
            acc[1][0] += a.y * b.x; acc[1][1] += a.y * b.y; acc[1][2] += a.y * b.z; acc[1][3] += a.y * b.w;
            acc[2][0] += a.z * b.x; acc[2][1] += a.z * b.y; acc[2][2] += a.z * b.z; acc[2][3] += a.z * b.w;
            acc[3][0] += a.w * b.x; acc[3][1] += a.w * b.y; acc[3][2] += a.w * b.z; acc[3][3] += a.w * b.w;
        }
        __syncthreads();
    }

    if (tx * 4 + 3 < NOUT) {
#pragma unroll
        for (int i = 0; i < 4; ++i) {
            int row = r0 + ty * 4 + i;
            if (row < nrows) {
                ushort4 hv;
                hv.x = f2bf(acc[i][0]); hv.y = f2bf(acc[i][1]);
                hv.z = f2bf(acc[i][2]); hv.w = f2bf(acc[i][3]);
                *(ushort4*)&HB[(size_t)row * NOUT + tx * 4] = hv;
            }
        }
    }
}

// Persistent GEMM (layers 1 & 2): grid-stride over row tiles; W stays L2-hot.
template<int K, int NOUT, bool RELU_IN>
__global__ __launch_bounds__(256) void k_gemm(
    const float* __restrict__ X, const float* __restrict__ W,
    unsigned short* __restrict__ HB, int nrows, int ntiles)
{
#pragma unroll 1
    for (int tile = (int)blockIdx.x; tile < ntiles; tile += (int)gridDim.x)
        gemm_tile_body<K, NOUT, RELU_IN>(X, W, HB, nrows, tile);
}

// Fused, INTERLEAVED: paired region [0, 2*min(ntiles,ncnt)): even=cnt,
// odd=gemm; tail = leftover blocks of the larger role.
template<int K, int NOUT, bool RELU_IN>
__global__ __launch_bounds__(256) void k_gemm_cnt(
    const float* __restrict__ X, const float* __restrict__ W,
    unsigned short* __restrict__ HB, int nrows, int ntiles, int ncnt,
    const int* __restrict__ dst, int* __restrict__ cnt, int* __restrict__ pos, int E)
{
    const int b  = (int)blockIdx.x;
    const int m  = min(ntiles, ncnt);
    bool isCnt; int idx;
    if (b < 2 * m) {
        isCnt = ((b & 1) == 0);
        idx   = b >> 1;
    } else {
        int rem = b - 2 * m;
        isCnt = (ncnt > ntiles);
        idx   = m + rem;
    }
    if (!isCnt) {
        gemm_tile_body<K, NOUT, RELU_IN>(X, W, HB, nrows, idx);
    } else {
        int e0     = idx * 256 + (int)threadIdx.x;
        int stride = ncnt * 256;
        for (int e = e0; e < E; e += stride)
            pos[e] = atomicAdd(&cnt[dst[e]], 1);
    }
}

// Gather aggregation: one wave per node, lane = feature. No atomics.
// Pairs staged via ONE coalesced 512B wave-load per 64 slots; unroll-4.
// NORMW (agg0 only): payload arrives as ew; lane computes nrm =
// dis[s]*ew*dis[row], writes the pair back (coalesced) and aggregates with
// nrm. Layers 1/2 then read nrm directly. k_place refreshes ew each launch.
template<int F, bool LSM, bool NORMW>
__global__ __launch_bounds__(256) void k_node_agg(
    const unsigned short* __restrict__ hB, const float* __restrict__ dis,
    const float* __restrict__ bias, const int* __restrict__ rowptr,
    unsigned long long* __restrict__ pairP,
    float* __restrict__ out, int n)
{
    __shared__ unsigned long long pl[4][64];   // 2KB: 64 pairs per wave
    const int lane = threadIdx.x & 63;
    const int wid  = (threadIdx.x >> 6) & 3;
    int row = (int)((blockIdx.x * blockDim.x + threadIdx.x) >> 6);
    if (row >= n) return;
    row = __builtin_amdgcn_readfirstlane(row);   // wave-uniform -> SGPR addrs

    const int a = rowptr[row], b = rowptr[row + 1];
    float d  = dis[row];
    float dd = d * d;
    float sum = 0.f;
    if (lane < F) sum = bf2f(hB[(size_t)row * F + lane]) * dd + bias[lane];

    for (int base = a; base < b; base += 64) {
        int idx = base + lane;
        unsigned long long pk = (idx < b) ? pairP[idx] : 0ull;  // coalesced 512B
        if (NORMW) {
            if (idx < b) {
                int   sl = (int)(unsigned int)pk;
                float wl = __uint_as_float((unsigned int)(pk >> 32));
                float nr = dis[sl] * wl * d;          // dis[s]*ew*dis[row]
                pk = ((unsigned long long)__float_as_uint(nr) << 32)
                   | (unsigned int)sl;
                pairP[idx] = pk;                      // coalesced write-back
            }
        }
        pl[wid][lane] = pk;
        int c = min(64, b - base);
        int j = 0;
        for (; j + 4 <= c; j += 4) {
            unsigned long long p0 = pl[wid][j],     p1 = pl[wid][j + 1];
            unsigned long long p2 = pl[wid][j + 2], p3 = pl[wid][j + 3];
            int   s0 = (int)(unsigned int)p0, s1 = (int)(unsigned int)p1;
            int   s2 = (int)(unsigned int)p2, s3 = (int)(unsigned int)p3;
            float w0 = __uint_as_float((unsigned int)(p0 >> 32));
            float w1 = __uint_as_float((unsigned int)(p1 >> 32));
            float w2 = __uint_as_float((unsigned int)(p2 >> 32));
            float w3 = __uint_as_float((unsigned int)(p3 >> 32));
            if (lane < F) {
                sum += bf2f(hB[(size_t)s0 * F + lane]) * w0;
                sum += bf2f(hB[(size_t)s1 * F + lane]) * w1;
                sum += bf2f(hB[(size_t)s2 * F + lane]) * w2;
                sum += bf2f(hB[(size_t)s3 * F + lane]) * w3;
            }
        }
        for (; j < c; ++j) {
            unsigned long long p = pl[wid][j];
            int s = (int)(unsigned int)p;
            float w = __uint_as_float((unsigned int)(p >> 32));
            if (lane < F) sum += bf2f(hB[(size_t)s * F + lane]) * w;
        }
    }

    if (LSM) {
        float v = (lane < F) ? sum : -INFINITY;
        float m = v;
#pragma unroll
        for (int off = 32; off; off >>= 1) m = fmaxf(m, __shfl_xor(m, off));
        float e = (lane < F) ? expf(v - m) : 0.f;
        float s2 = e;
#pragma unroll
        for (int off = 32; off; off >>= 1) s2 += __shfl_xor(s2, off);
        float ls = logf(s2);
        if (lane < F) out[(size_t)row * F + lane] = v - m - ls;
    } else {
        if (lane < F) out[(size_t)row * F + lane] = sum;
    }
}

extern "C" void kernel_launch(void* const* d_in, const int* in_sizes, int n_in,
                              void* d_out, int out_size, void* d_ws, size_t ws_size,
                              hipStream_t stream) {
    const float* x  = (const float*)d_in[0];
    const int*   ei = (const int*)  d_in[1];
    const float* ew = (const float*)d_in[2];
    const float* W0 = (const float*)d_in[3];
    const float* b0 = (const float*)d_in[4];
    const float* W1 = (const float*)d_in[5];
    const float* b1 = (const float*)d_in[6];
    const float* W2 = (const float*)d_in[7];
    const float* b2 = (const float*)d_in[8];

    const int E   = in_sizes[2];            // 1600000
    const int H   = in_sizes[4];            // 64
    const int Fin = in_sizes[3] / H;        // 256
    const int N   = in_sizes[0] / Fin;      // 100000
    (void)n_in; (void)out_size; (void)ws_size;

    const int* srcv = ei;                   // edge_index[0]
    const int* dstv = ei + E;               // edge_index[1]

    // ---- workspace layout ----
    float* ws = (float*)d_ws;
    size_t o = 0;
    auto alloc = [&](size_t cnt_) { size_t p = o; o += (cnt_ + 63) & ~(size_t)63; return p; };
    float* dis   = ws + alloc(N);
    float* bufB  = ws + alloc((size_t)N * 64);               // agg out (fp32 trunk)
    unsigned short* hB = (unsigned short*)(ws + alloc((size_t)N * 32));  // bf16 h
    unsigned long long* pairP = (unsigned long long*)(ws + alloc((size_t)E * 2));
    int*   rowptr= (int*)(ws + alloc(N + 1));
    int*   cnt   = (int*)(ws + alloc(N));
    int*   pos   = (int*)(ws + alloc(E));
    int*   bsum  = (int*)(ws + alloc(512));
    float* outf  = (float*)d_out;                            // N*40

    const int TB  = 256;
    const int nb1 = (N + 255) / 256;                 // scan blocks (391)
    const int ntiles = (N + 63) / 64;                // 1563 gemm tiles
    const int XB  = 256;                             // cnt blocks (R24: back to 256)

    // ---- fused interleaved: gemm L0 || counting histogram ----
    (void)hipMemsetAsync(cnt, 0, (size_t)N * sizeof(int), stream);
    {
        const int m = (ntiles < XB) ? ntiles : XB;
        const int grid = 2 * m + ((ntiles > XB) ? (ntiles - XB) : (XB - ntiles));
        k_gemm_cnt<256, 64, false><<<grid, TB, 0, stream>>>(
            x, W0, hB, N, ntiles, XB, dstv, cnt, pos, E);
    }

    // ---- scan cnt -> rowptr (2 kernels) ----
    k_scan1 <<<nb1, 256, 0, stream>>>(cnt, rowptr, bsum, N);
    k_scan3m<<<nb1, 256, 0, stream>>>(rowptr, bsum, N, E);

    // ---- place packed pairs (no atomic; payload = ew) ----
    k_place<<<(E + TB - 1) / TB, TB, 0, stream>>>(srcv, dstv, ew, rowptr, pos, pairP, E);

    const int aggGrid = (N * 64 + TB - 1) / TB;      // one wave per node

    // ---- dis over CSR (wave-per-node, coalesced) ----
    k_deg_dis<<<aggGrid, TB, 0, stream>>>(pairP, rowptr, dis, N);

    // ---- layer 0 aggregate + fused norm rewrite (ew -> nrm in pairP) ----
    k_node_agg<64, false, true><<<aggGrid, TB, 0, stream>>>(hB, dis, b0, rowptr, pairP, bufB, N);

    // ---- layer 1: 64 -> 64 (relu on load), persistent grid ----
    k_gemm<64, 64, true><<<512, TB, 0, stream>>>(bufB, W1, hB, N, ntiles);
    k_node_agg<64, false, false><<<aggGrid, TB, 0, stream>>>(hB, dis, b1, rowptr, pairP, bufB, N);

    // ---- layer 2: 64 -> 40, aggregate + fused log_softmax into d_out ----
    k_gemm<64, 40, true><<<512, TB, 0, stream>>>(bufB, W2, hB, N, ntiles);
    k_node_agg<40, true, false><<<aggGrid, TB, 0, stream>>>(hB, dis, b2, rowptr, pairP, outf, N);
}